// Round 4
// baseline (98.925 us; speedup 1.0000x reference)
//
#include <hip/hip_runtime.h>
#include <cstdint>
#include <math.h>

#define B_SAMP 4096
#define D_DIM  128
#define N_ROWS 8192
#define NCLS   64
#define NCHUNK 16
#define CCHUNK 512
#define TC     64
#define NTILE  (CCHUNK / TC)
#define THR_DOT 2.1f   // = 30 logit units; dropped terms < e^-30 relative to running max

typedef __attribute__((ext_vector_type(8))) short short8;
typedef __attribute__((ext_vector_type(4))) float f32x4;

__device__ __forceinline__ float inv_temp() { return 1.0f / (0.07f + 1e-8f); }

__device__ __forceinline__ void jac(int a, int b, float& mv, float& mk) {
    int u = __popc(a & b);
    int l = __popc(a | b);
    mv = (float)u / ((float)l + 1e-8f);
    mk = (mv >= 0.3f) ? 1.0f : 0.0f;
}

__device__ __forceinline__ ushort bf16rne(float x) {
    uint u = __float_as_uint(x);
    u += 0x7FFF + ((u >> 16) & 1);
    return (ushort)(u >> 16);
}

// ---------------- K0: zero accumulators ----------------
__global__ void k_zero(float* F, int* count) {
    int t = threadIdx.x;
    for (int i = t; i < NCLS * D_DIM; i += 256) F[i] = 0.0f;
    if (t < NCLS) count[t] = 0;
}

// ---------------- K1: fused label-pack + bf16 cast + per-class sums + row norms ----------------
// grid 64 blocks x 256 thr; block b handles rows n0..n0+127 (one view).
__global__ void k_castfeat(const float* __restrict__ feats, const int* __restrict__ labels,
                           int* __restrict__ cls, int* __restrict__ count,
                           float* __restrict__ F, ushort* __restrict__ fb,
                           float* __restrict__ nrm2v) {
    __shared__ float loc[NCLS * D_DIM];   // 32 KiB
    __shared__ int cls_loc[128];
    int b = blockIdx.x;
    int t = threadIdx.x;
    int n0 = b * 128;
    int s0 = n0 & (B_SAMP - 1);
    int view = n0 >> 12;
    for (int i = t; i < NCLS * D_DIM; i += 256) loc[i] = 0.0f;
    if (t < 128) {
        int c = 0;
#pragma unroll
        for (int k = 0; k < 6; k++) c |= (labels[(s0 + t) * 6 + k] != 0) << k;
        cls_loc[t] = c;
        if (view == 0) { cls[s0 + t] = c; atomicAdd(&count[c], 1); }
    }
    __syncthreads();
    // 128 rows x 32 float4 quads: halfwave (32 lanes) h handles row h + 8k in iter k
    for (int q = t; q < 128 * 32; q += 256) {
        int r = q >> 5, d4 = (q & 31) * 4;
        const float* src = feats + (size_t)(s0 + r) * 256 + (size_t)view * 128 + d4;
        float4 v = *(const float4*)src;
        ushort4 h;
        h.x = bf16rne(v.x); h.y = bf16rne(v.y); h.z = bf16rne(v.z); h.w = bf16rne(v.w);
        *(ushort4*)&fb[(size_t)(n0 + r) * D_DIM + d4] = h;
        float* lrow = &loc[cls_loc[r] * D_DIM + d4];
        atomicAdd(&lrow[0], v.x); atomicAdd(&lrow[1], v.y);
        atomicAdd(&lrow[2], v.z); atomicAdd(&lrow[3], v.w);
        // fp32 row norm^2 -> exact diagonal logit (the row max) for k_gemm's m-init
        float qs = v.x * v.x + v.y * v.y + v.z * v.z + v.w * v.w;
#pragma unroll
        for (int o = 16; o; o >>= 1) qs += __shfl_xor(qs, o);
        if ((t & 31) == 0) nrm2v[n0 + r] = qs;
    }
    __syncthreads();
    for (int i = t; i < NCLS * D_DIM; i += 256) {
        float v = loc[i];
        if (v != 0.0f) atomicAdd(&F[i], v);
    }
}

// ---------------- K2: class tables G, Wm, W, diag terms ----------------
__global__ void k_tables(const float* __restrict__ F, const int* __restrict__ count,
                         float* G, float* WmC, float* WC, float* gdiag, float* mdiag) {
    int c = blockIdx.x;
    int d = threadIdx.x;
    float sum = 0.0f;
    for (int c2 = 0; c2 < NCLS; c2++) {
        float mv, mk; jac(c, c2, mv, mk);
        sum += mv * mk * F[c2 * D_DIM + d];
    }
    G[c * D_DIM + d] = sum;
    if (d == 0) {
        float wm = 0.0f, wv = 0.0f;
        for (int c2 = 0; c2 < NCLS; c2++) {
            float mv, mk; jac(c, c2, mv, mk);
            float cnt2 = 2.0f * (float)count[c2];
            wm += mv * mk * cnt2;
            wv += mk * cnt2;
        }
        float mv, mk; jac(c, c, mv, mk);
        WmC[c] = wm; WC[c] = wv; gdiag[c] = mv * mk; mdiag[c] = mk;
    }
}

// ---------------- K3: bf16 MFMA GEMM, m init'd at diag norm, wave-uniform skip ----------------
// grid: 512 blocks = 32 row-blocks (256 rows) x 16 col-chunks (512 cols); 4 waves/block.
// Round-3 lesson: per-lane divergent exp branches made this VALU-bound (53% VALUBusy,
// 15% MfmaUtil). m[idx] starts at the fp32 diagonal (provable row max candidate), so
// cross-dot tiles are ~never within THR -> one __any() branch per tile, ~always skipped.
__launch_bounds__(256, 1)
__global__ void k_gemm4(const ushort* __restrict__ fb, const float* __restrict__ nrm2v,
                        float* __restrict__ pm, float* __restrict__ ps) {
    __shared__ ushort Bs[2][TC * D_DIM];   // 2 x 16 KiB
    const float invT = inv_temp();
    int tid = threadIdx.x;
    int lane = tid & 63, w = tid >> 6;
    int rowBlk = blockIdx.x & 31;
    int chunk  = blockIdx.x >> 5;
    int rowbase = rowBlk * 256 + w * 64;
    int colChunk = chunk * CCHUNK;
    int r0 = (lane >> 4) * 4;

    // A fragments: lane holds row = rowbase + rf*16 + (lane&15), k = kk*32 + (lane>>4)*8 .. +8
    short8 a[4][4];
    {
        int r = lane & 15, kb = (lane >> 4) * 8;
#pragma unroll
        for (int rf = 0; rf < 4; rf++)
#pragma unroll
            for (int kk = 0; kk < 4; kk++)
                a[rf][kk] = *(const short8*)&fb[(size_t)(rowbase + rf * 16 + r) * D_DIM + kk * 32 + kb];
    }

    // staging source offsets (ushort units), pre-swizzled: LDS[col][chunk] = glob[col][chunk ^ (col&7)]
    int sOff[4];
#pragma unroll
    for (int j = 0; j < 4; j++) {
        int c = (w * 4 + j) * 4 + (lane >> 4);
        int sw = (lane & 15) ^ (c & 7);
        sOff[j] = c * D_DIM + sw * 8;
    }

    float m[16], s[16];
#pragma unroll
    for (int rf = 0; rf < 4; rf++)
#pragma unroll
        for (int r = 0; r < 4; r++) {
            m[rf * 4 + r] = nrm2v[rowbase + rf * 16 + r0 + r];
            s[rf * 4 + r] = 0.0f;
        }

    // prologue: stage tile 0 -> buf 0
#pragma unroll
    for (int j = 0; j < 4; j++) {
        const ushort* g = fb + (size_t)colChunk * D_DIM + sOff[j];
        __builtin_amdgcn_global_load_lds((const __attribute__((address_space(1))) void*)g,
            (__attribute__((address_space(3))) void*)&Bs[0][(w * 4 + j) * 512], 16, 0, 0);
    }
    __syncthreads();

    for (int t = 0; t < NTILE; t++) {
        int cur = t & 1;
        if (t + 1 < NTILE) {
#pragma unroll
            for (int j = 0; j < 4; j++) {
                const ushort* g = fb + (size_t)(colChunk + (t + 1) * TC) * D_DIM + sOff[j];
                __builtin_amdgcn_global_load_lds((const __attribute__((address_space(1))) void*)g,
                    (__attribute__((address_space(3))) void*)&Bs[cur ^ 1][(w * 4 + j) * 512], 16, 0, 0);
            }
        }

        f32x4 acc[4][4];
#pragma unroll
        for (int rf = 0; rf < 4; rf++)
#pragma unroll
            for (int cf = 0; cf < 4; cf++)
                acc[rf][cf] = (f32x4){0.f, 0.f, 0.f, 0.f};

#pragma unroll
        for (int cf = 0; cf < 4; cf++) {
            int col = cf * 16 + (lane & 15);
            short8 b[4];
#pragma unroll
            for (int kk = 0; kk < 4; kk++) {
                int sw = (kk * 4 + (lane >> 4)) ^ (lane & 7);
                b[kk] = *(const short8*)&Bs[cur][col * D_DIM + sw * 8];
            }
#pragma unroll
            for (int rf = 0; rf < 4; rf++)
#pragma unroll
                for (int kk = 0; kk < 4; kk++)
                    acc[rf][cf] = __builtin_amdgcn_mfma_f32_16x16x32_bf16(a[rf][kk], b[kk], acc[rf][cf], 0, 0, 0);
        }

        // wave-uniform activity test: any idx whose tile-max encroaches on its running max
        float tmax[16];
        int act = 0;
#pragma unroll
        for (int rf = 0; rf < 4; rf++)
#pragma unroll
            for (int r = 0; r < 4; r++) {
                int idx = rf * 4 + r;
                float t0 = fmaxf(acc[rf][0][r], acc[rf][1][r]);
                float t1 = fmaxf(acc[rf][2][r], acc[rf][3][r]);
                tmax[idx] = fmaxf(t0, t1);
                act |= (tmax[idx] > m[idx] - THR_DOT) ? 1 : 0;
            }
        if (__any(act)) {
            int tileCol = colChunk + t * TC + (lane & 15);
#pragma unroll
            for (int rf = 0; rf < 4; rf++)
#pragma unroll
                for (int r = 0; r < 4; r++) {
                    int idx = rf * 4 + r;
                    int grow = rowbase + rf * 16 + r0 + r;
                    float nm = fmaxf(m[idx], tmax[idx]);
                    float sc = __expf((m[idx] - nm) * invT);
                    float v0 = acc[rf][0][r], v1 = acc[rf][1][r], v2 = acc[rf][2][r], v3 = acc[rf][3][r];
                    float e0 = (tileCol      == grow) ? 0.f : __expf((v0 - nm) * invT);
                    float e1 = (tileCol + 16 == grow) ? 0.f : __expf((v1 - nm) * invT);
                    float e2 = (tileCol + 32 == grow) ? 0.f : __expf((v2 - nm) * invT);
                    float e3 = (tileCol + 48 == grow) ? 0.f : __expf((v3 - nm) * invT);
                    s[idx] = s[idx] * sc + ((e0 + e1) + (e2 + e3));
                    m[idx] = nm;
                }
        }
        __syncthreads();
    }

    // merge the 16 col-slot partials (xor over low 4 lane bits)
#pragma unroll
    for (int i = 0; i < 16; i++) {
#pragma unroll
        for (int off = 1; off < 16; off <<= 1) {
            float om = __shfl_xor(m[i], off);
            float os = __shfl_xor(s[i], off);
            float nm = fmaxf(m[i], om);
            s[i] = s[i] * __expf((m[i] - nm) * invT) + os * __expf((om - nm) * invT);
            m[i] = nm;
        }
    }
    if ((lane & 15) == 0) {
#pragma unroll
        for (int rf = 0; rf < 4; rf++)
#pragma unroll
            for (int r = 0; r < 4; r++) {
                int grow = rowbase + rf * 16 + r0 + r;
                pm[chunk * N_ROWS + grow] = m[rf * 4 + r];
                ps[chunk * N_ROWS + grow] = s[rf * 4 + r];
            }
    }
}

// ---------------- K4: fused chunk-merge + f.G / ||f||^2 + per-row loss ----------------
// grid 2048 x 256: one wave per row.
__global__ void k_final2(const float* __restrict__ feats, const int* __restrict__ cls,
                         const float* __restrict__ G, const float* __restrict__ pm,
                         const float* __restrict__ ps, const float* __restrict__ WmC,
                         const float* __restrict__ WC, const float* __restrict__ gdiag,
                         const float* __restrict__ mdiag, float* __restrict__ partial) {
    const float invT = inv_temp();
    __shared__ float red[4];
    int tid = threadIdx.x;
    int lane = tid & 63, w = tid >> 6;
    int n = blockIdx.x * 4 + w;
    int samp = n & (B_SAMP - 1), view = n >> 12;
    int c = cls[samp];
    const float* f = feats + (size_t)samp * 256 + (size_t)view * 128;
    const float* g = G + (size_t)c * D_DIM;
    float2 fv = *(const float2*)(f + lane * 2);
    float2 gv = *(const float2*)(g + lane * 2);
    float dg = fv.x * gv.x + fv.y * gv.y;
    float nn = fv.x * fv.x + fv.y * fv.y;
#pragma unroll
    for (int o = 32; o; o >>= 1) { dg += __shfl_down(dg, o); nn += __shfl_down(nn, o); }
    dg = __shfl(dg, 0); nn = __shfl(nn, 0);

    float m = -INFINITY, s = 0.0f;
    if (lane < 16) { m = pm[lane * N_ROWS + n]; s = ps[lane * N_ROWS + n]; }
#pragma unroll
    for (int off = 8; off; off >>= 1) {
        float om = __shfl_xor(m, off);
        float os = __shfl_xor(s, off);
        float nm = fmaxf(m, om);
        s = s * __expf((m - nm) * invT) + os * __expf((om - nm) * invT);
        m = nm;
    }
    if (lane == 0) {
        float wm = WmC[c] - gdiag[c];
        float wv = WC[c] - mdiag[c];
        float swl = (dg - gdiag[c] * nn) * invT;
        float lp = swl - wm * (m * invT) - wm * logf(s + 1e-8f);
        red[w] = -lp / (wv + 1e-8f);
    }
    __syncthreads();
    if (tid == 0) partial[blockIdx.x] = (red[0] + red[1]) + (red[2] + red[3]);
}

// ---------------- K5: final deterministic reduce ----------------
__global__ void k_out(const float* __restrict__ partial, float* out) {
    __shared__ float red[4];
    int t = threadIdx.x;
    float s = 0.0f;
    for (int i = t; i < 2048; i += 256) s += partial[i];
#pragma unroll
    for (int o = 32; o; o >>= 1) s += __shfl_down(s, o);
    if ((t & 63) == 0) red[t >> 6] = s;
    __syncthreads();
    if (t == 0) out[0] = ((red[0] + red[1]) + (red[2] + red[3])) / (float)N_ROWS;
}

extern "C" void kernel_launch(void* const* d_in, const int* in_sizes, int n_in,
                              void* d_out, int out_size, void* d_ws, size_t ws_size,
                              hipStream_t stream) {
    const float* feats  = (const float*)d_in[0];
    const int*   labels = (const int*)d_in[1];
    float* out = (float*)d_out;

    char* ws = (char*)d_ws;
    ushort* fb    = (ushort*)ws;              ws += (size_t)N_ROWS * D_DIM * 2;      // 2 MiB
    float* pm     = (float*)ws;               ws += (size_t)NCHUNK * N_ROWS * 4;     // 512 KiB
    float* ps     = (float*)ws;               ws += (size_t)NCHUNK * N_ROWS * 4;     // 512 KiB
    int*   cls    = (int*)ws;                 ws += B_SAMP * 4;
    int*   count  = (int*)ws;                 ws += NCLS * 4;
    float* F      = (float*)ws;               ws += NCLS * D_DIM * 4;
    float* G      = (float*)ws;               ws += NCLS * D_DIM * 4;
    float* WmC    = (float*)ws;               ws += NCLS * 4;
    float* WC     = (float*)ws;               ws += NCLS * 4;
    float* gdiag  = (float*)ws;               ws += NCLS * 4;
    float* mdiag  = (float*)ws;               ws += NCLS * 4;
    float* nrm2v  = (float*)ws;               ws += N_ROWS * 4;
    float* partial= (float*)ws;               ws += 2048 * 4;

    k_zero    <<<1, 256, 0, stream>>>(F, count);
    k_castfeat<<<64, 256, 0, stream>>>(feats, labels, cls, count, F, fb, nrm2v);
    k_tables  <<<NCLS, 128, 0, stream>>>(F, count, G, WmC, WC, gdiag, mdiag);
    k_gemm4   <<<512, 256, 0, stream>>>(fb, nrm2v, pm, ps);
    k_final2  <<<2048, 256, 0, stream>>>(feats, cls, G, pm, ps, WmC, WC, gdiag, mdiag, partial);
    k_out     <<<1, 256, 0, stream>>>(partial, out);
}

// Round 5
// 93.965 us; speedup vs baseline: 1.0528x; 1.0528x over previous
//
#include <hip/hip_runtime.h>
#include <cstdint>
#include <math.h>

#define B_SAMP 4096
#define D_DIM  128
#define N_ROWS 8192
#define NCLS   64
#define NCHUNK 16
#define CCHUNK 512
#define TC     64
#define NTILE  (CCHUNK / TC)
#define THR_DOT 2.1f   // = 30 logit units; dropped terms < e^-30 relative to running max

typedef __attribute__((ext_vector_type(8))) short short8;
typedef __attribute__((ext_vector_type(4))) float f32x4;

__device__ __forceinline__ float inv_temp() { return 1.0f / (0.07f + 1e-8f); }

__device__ __forceinline__ void jac(int a, int b, float& mv, float& mk) {
    int u = __popc(a & b);
    int l = __popc(a | b);
    mv = (float)u / ((float)l + 1e-8f);
    mk = (mv >= 0.3f) ? 1.0f : 0.0f;
}

__device__ __forceinline__ ushort bf16rne(float x) {
    uint u = __float_as_uint(x);
    u += 0x7FFF + ((u >> 16) & 1);
    return (ushort)(u >> 16);
}

// ---------------- K0: zero accumulators ----------------
__global__ void k_zero(float* F, int* count) {
    int t = threadIdx.x;
    for (int i = t; i < NCLS * D_DIM; i += 256) F[i] = 0.0f;
    if (t < NCLS) count[t] = 0;
}

// ---------------- K1: fused label-pack + bf16 cast + per-class sums + row norms ----------------
// grid 128 blocks x 256 thr; block b handles rows n0..n0+63 (one view).
__global__ void k_castfeat(const float* __restrict__ feats, const int* __restrict__ labels,
                           int* __restrict__ cls, int* __restrict__ count,
                           float* __restrict__ F, ushort* __restrict__ fb,
                           float* __restrict__ nrm2v) {
    __shared__ float loc[NCLS * D_DIM];   // 32 KiB
    __shared__ int cls_loc[64];
    int b = blockIdx.x;
    int t = threadIdx.x;
    int n0 = b * 64;
    int s0 = n0 & (B_SAMP - 1);
    int view = n0 >> 12;
    for (int i = t; i < NCLS * D_DIM; i += 256) loc[i] = 0.0f;
    if (t < 64) {
        int c = 0;
#pragma unroll
        for (int k = 0; k < 6; k++) c |= (labels[(s0 + t) * 6 + k] != 0) << k;
        cls_loc[t] = c;
        if (view == 0) { cls[s0 + t] = c; atomicAdd(&count[c], 1); }
    }
    __syncthreads();
    // 64 rows x 32 float4 quads
    for (int q = t; q < 64 * 32; q += 256) {
        int r = q >> 5, d4 = (q & 31) * 4;
        const float* src = feats + (size_t)(s0 + r) * 256 + (size_t)view * 128 + d4;
        float4 v = *(const float4*)src;
        ushort4 h;
        h.x = bf16rne(v.x); h.y = bf16rne(v.y); h.z = bf16rne(v.z); h.w = bf16rne(v.w);
        *(ushort4*)&fb[(size_t)(n0 + r) * D_DIM + d4] = h;
        float* lrow = &loc[cls_loc[r] * D_DIM + d4];
        atomicAdd(&lrow[0], v.x); atomicAdd(&lrow[1], v.y);
        atomicAdd(&lrow[2], v.z); atomicAdd(&lrow[3], v.w);
        // fp32 row norm^2 -> exact diagonal logit (the row-max candidate) for k_gemm's m-init
        float qs = v.x * v.x + v.y * v.y + v.z * v.z + v.w * v.w;
#pragma unroll
        for (int o = 16; o; o >>= 1) qs += __shfl_xor(qs, o);
        if ((t & 31) == 0) nrm2v[n0 + r] = qs;
    }
    __syncthreads();
    for (int i = t; i < NCLS * D_DIM; i += 256) {
        float v = loc[i];
        if (v != 0.0f) atomicAdd(&F[i], v);
    }
}

// ---------------- K2: class tables G, Wm, W, diag terms ----------------
__global__ void k_tables(const float* __restrict__ F, const int* __restrict__ count,
                         float* G, float* WmC, float* WC, float* gdiag, float* mdiag) {
    int c = blockIdx.x;
    int d = threadIdx.x;
    float sum = 0.0f;
    for (int c2 = 0; c2 < NCLS; c2++) {
        float mv, mk; jac(c, c2, mv, mk);
        sum += mv * mk * F[c2 * D_DIM + d];
    }
    G[c * D_DIM + d] = sum;
    if (d == 0) {
        float wm = 0.0f, wv = 0.0f;
        for (int c2 = 0; c2 < NCLS; c2++) {
            float mv, mk; jac(c, c2, mv, mk);
            float cnt2 = 2.0f * (float)count[c2];
            wm += mv * mk * cnt2;
            wv += mk * cnt2;
        }
        float mv, mk; jac(c, c, mv, mk);
        WmC[c] = wm; WC[c] = wv; gdiag[c] = mv * mk; mdiag[c] = mk;
    }
}

// ---------------- K3: bf16 MFMA GEMM, NO LDS / NO BARRIERS ----------------
// Round-4 lesson: three different inner loops all pinned at 41us with MFMA 15% /
// VALU 22% / occ 8% -- the global_load_lds + vmcnt(0)-drain-before-barrier
// structure was the bottleneck, not ALU work. fb is 2MB (L2-resident), so read
// B fragments straight from L2 into registers; waves run with zero sync.
// grid: 512 blocks = 32 row-blocks (256 rows) x 16 col-chunks; 4 waves/block,
// wave owns 64 rows x 512 cols, 8 tiles of 64 cols.
__launch_bounds__(256, 1)
__global__ void k_gemm5(const ushort* __restrict__ fb, const float* __restrict__ nrm2v,
                        float* __restrict__ pm, float* __restrict__ ps) {
    const float invT = inv_temp();
    int tid = threadIdx.x;
    int lane = tid & 63, w = tid >> 6;
    int rowBlk = blockIdx.x & 31;
    int chunk  = blockIdx.x >> 5;
    int rowbase = rowBlk * 256 + w * 64;
    int colChunk = chunk * CCHUNK;
    int r0 = (lane >> 4) * 4;

    // A fragments: lane holds row = rowbase + rf*16 + (lane&15), k = kk*32 + (lane>>4)*8 .. +8
    short8 a[4][4];
    {
        int r = lane & 15, kb = (lane >> 4) * 8;
#pragma unroll
        for (int rf = 0; rf < 4; rf++)
#pragma unroll
            for (int kk = 0; kk < 4; kk++)
                a[rf][kk] = *(const short8*)&fb[(size_t)(rowbase + rf * 16 + r) * D_DIM + kk * 32 + kb];
    }

    float m[16], s[16];
#pragma unroll
    for (int rf = 0; rf < 4; rf++)
#pragma unroll
        for (int r = 0; r < 4; r++) {
            m[rf * 4 + r] = nrm2v[rowbase + rf * 16 + r0 + r];
            s[rf * 4 + r] = 0.0f;
        }

    // B base: lane reads col (lane&15) of each 16-col group, k-slice (lane>>4)*8
    const ushort* bbase = fb + ((size_t)colChunk + (lane & 15)) * D_DIM + (lane >> 4) * 8;

    for (int t = 0; t < NTILE; t++) {
        // 16 direct global loads (L2-hit) for this 64-col tile
        short8 b[4][4];
#pragma unroll
        for (int cf = 0; cf < 4; cf++)
#pragma unroll
            for (int kk = 0; kk < 4; kk++)
                b[cf][kk] = *(const short8*)(bbase + ((size_t)(t * TC + cf * 16)) * D_DIM + kk * 32);

        f32x4 acc[4][4];
#pragma unroll
        for (int rf = 0; rf < 4; rf++)
#pragma unroll
            for (int cf = 0; cf < 4; cf++)
                acc[rf][cf] = (f32x4){0.f, 0.f, 0.f, 0.f};

#pragma unroll
        for (int cf = 0; cf < 4; cf++)
#pragma unroll
            for (int rf = 0; rf < 4; rf++)
#pragma unroll
                for (int kk = 0; kk < 4; kk++)
                    acc[rf][cf] = __builtin_amdgcn_mfma_f32_16x16x32_bf16(a[rf][kk], b[cf][kk], acc[rf][cf], 0, 0, 0);

        // wave-uniform activity test: any idx whose tile-max encroaches on its running max
        float tmax[16];
        int act = 0;
#pragma unroll
        for (int rf = 0; rf < 4; rf++)
#pragma unroll
            for (int r = 0; r < 4; r++) {
                int idx = rf * 4 + r;
                float t0 = fmaxf(acc[rf][0][r], acc[rf][1][r]);
                float t1 = fmaxf(acc[rf][2][r], acc[rf][3][r]);
                tmax[idx] = fmaxf(t0, t1);
                act |= (tmax[idx] > m[idx] - THR_DOT) ? 1 : 0;
            }
        if (__any(act)) {
            int tileCol = colChunk + t * TC + (lane & 15);
#pragma unroll
            for (int rf = 0; rf < 4; rf++)
#pragma unroll
                for (int r = 0; r < 4; r++) {
                    int idx = rf * 4 + r;
                    int grow = rowbase + rf * 16 + r0 + r;
                    float nm = fmaxf(m[idx], tmax[idx]);
                    float sc = __expf((m[idx] - nm) * invT);
                    float v0 = acc[rf][0][r], v1 = acc[rf][1][r], v2 = acc[rf][2][r], v3 = acc[rf][3][r];
                    float e0 = (tileCol      == grow) ? 0.f : __expf((v0 - nm) * invT);
                    float e1 = (tileCol + 16 == grow) ? 0.f : __expf((v1 - nm) * invT);
                    float e2 = (tileCol + 32 == grow) ? 0.f : __expf((v2 - nm) * invT);
                    float e3 = (tileCol + 48 == grow) ? 0.f : __expf((v3 - nm) * invT);
                    s[idx] = s[idx] * sc + ((e0 + e1) + (e2 + e3));
                    m[idx] = nm;
                }
        }
    }

    // merge the 16 col-slot partials (xor over low 4 lane bits)
#pragma unroll
    for (int i = 0; i < 16; i++) {
#pragma unroll
        for (int off = 1; off < 16; off <<= 1) {
            float om = __shfl_xor(m[i], off);
            float os = __shfl_xor(s[i], off);
            float nm = fmaxf(m[i], om);
            s[i] = s[i] * __expf((m[i] - nm) * invT) + os * __expf((om - nm) * invT);
            m[i] = nm;
        }
    }
    if ((lane & 15) == 0) {
#pragma unroll
        for (int rf = 0; rf < 4; rf++)
#pragma unroll
            for (int r = 0; r < 4; r++) {
                int grow = rowbase + rf * 16 + r0 + r;
                pm[chunk * N_ROWS + grow] = m[rf * 4 + r];
                ps[chunk * N_ROWS + grow] = s[rf * 4 + r];
            }
    }
}

// ---------------- K4: fused chunk-merge + f.G / ||f||^2 + per-row loss ----------------
// grid 2048 x 256: one wave per row.
__global__ void k_final2(const float* __restrict__ feats, const int* __restrict__ cls,
                         const float* __restrict__ G, const float* __restrict__ pm,
                         const float* __restrict__ ps, const float* __restrict__ WmC,
                         const float* __restrict__ WC, const float* __restrict__ gdiag,
                         const float* __restrict__ mdiag, float* __restrict__ partial) {
    const float invT = inv_temp();
    __shared__ float red[4];
    int tid = threadIdx.x;
    int lane = tid & 63, w = tid >> 6;
    int n = blockIdx.x * 4 + w;
    int samp = n & (B_SAMP - 1), view = n >> 12;
    int c = cls[samp];
    const float* f = feats + (size_t)samp * 256 + (size_t)view * 128;
    const float* g = G + (size_t)c * D_DIM;
    float2 fv = *(const float2*)(f + lane * 2);
    float2 gv = *(const float2*)(g + lane * 2);
    float dg = fv.x * gv.x + fv.y * gv.y;
    float nn = fv.x * fv.x + fv.y * fv.y;
#pragma unroll
    for (int o = 32; o; o >>= 1) { dg += __shfl_down(dg, o); nn += __shfl_down(nn, o); }
    dg = __shfl(dg, 0); nn = __shfl(nn, 0);

    float m = -INFINITY, s = 0.0f;
    if (lane < 16) { m = pm[lane * N_ROWS + n]; s = ps[lane * N_ROWS + n]; }
#pragma unroll
    for (int off = 8; off; off >>= 1) {
        float om = __shfl_xor(m, off);
        float os = __shfl_xor(s, off);
        float nm = fmaxf(m, om);
        s = s * __expf((m - nm) * invT) + os * __expf((om - nm) * invT);
        m = nm;
    }
    if (lane == 0) {
        float wm = WmC[c] - gdiag[c];
        float wv = WC[c] - mdiag[c];
        float swl = (dg - gdiag[c] * nn) * invT;
        float lp = swl - wm * (m * invT) - wm * logf(s + 1e-8f);
        red[w] = -lp / (wv + 1e-8f);
    }
    __syncthreads();
    if (tid == 0) partial[blockIdx.x] = (red[0] + red[1]) + (red[2] + red[3]);
}

// ---------------- K5: final deterministic reduce ----------------
__global__ void k_out(const float* __restrict__ partial, float* out) {
    __shared__ float red[4];
    int t = threadIdx.x;
    float s = 0.0f;
    for (int i = t; i < 2048; i += 256) s += partial[i];
#pragma unroll
    for (int o = 32; o; o >>= 1) s += __shfl_down(s, o);
    if ((t & 63) == 0) red[t >> 6] = s;
    __syncthreads();
    if (t == 0) out[0] = ((red[0] + red[1]) + (red[2] + red[3])) / (float)N_ROWS;
}

extern "C" void kernel_launch(void* const* d_in, const int* in_sizes, int n_in,
                              void* d_out, int out_size, void* d_ws, size_t ws_size,
                              hipStream_t stream) {
    const float* feats  = (const float*)d_in[0];
    const int*   labels = (const int*)d_in[1];
    float* out = (float*)d_out;

    char* ws = (char*)d_ws;
    ushort* fb    = (ushort*)ws;              ws += (size_t)N_ROWS * D_DIM * 2;      // 2 MiB
    float* pm     = (float*)ws;               ws += (size_t)NCHUNK * N_ROWS * 4;     // 512 KiB
    float* ps     = (float*)ws;               ws += (size_t)NCHUNK * N_ROWS * 4;     // 512 KiB
    int*   cls    = (int*)ws;                 ws += B_SAMP * 4;
    int*   count  = (int*)ws;                 ws += NCLS * 4;
    float* F      = (float*)ws;               ws += NCLS * D_DIM * 4;
    float* G      = (float*)ws;               ws += NCLS * D_DIM * 4;
    float* WmC    = (float*)ws;               ws += NCLS * 4;
    float* WC     = (float*)ws;               ws += NCLS * 4;
    float* gdiag  = (float*)ws;               ws += NCLS * 4;
    float* mdiag  = (float*)ws;               ws += NCLS * 4;
    float* nrm2v  = (float*)ws;               ws += N_ROWS * 4;
    float* partial= (float*)ws;               ws += 2048 * 4;

    k_zero    <<<1, 256, 0, stream>>>(F, count);
    k_castfeat<<<128, 256, 0, stream>>>(feats, labels, cls, count, F, fb, nrm2v);
    k_tables  <<<NCLS, 128, 0, stream>>>(F, count, G, WmC, WC, gdiag, mdiag);
    k_gemm5   <<<512, 256, 0, stream>>>(fb, nrm2v, pm, ps);
    k_final2  <<<2048, 256, 0, stream>>>(feats, cls, G, pm, ps, WmC, WC, gdiag, mdiag, partial);
    k_out     <<<1, 256, 0, stream>>>(partial, out);
}

// Round 6
// 77.394 us; speedup vs baseline: 1.2782x; 1.2141x over previous
//
#include <hip/hip_runtime.h>
#include <cstdint>
#include <math.h>

#define B_SAMP 4096
#define D_DIM  128
#define N_ROWS 8192
#define NCLS   64
#define NCHUNK 16
#define CCHUNK 512
#define TC     64
#define NTILE  (CCHUNK / TC)
#define THR_DOT 2.1f   // = 30 logit units; dropped terms < e^-30 relative to running max

typedef __attribute__((ext_vector_type(8))) short short8;
typedef __attribute__((ext_vector_type(4))) float f32x4;

__device__ __forceinline__ float inv_temp() { return 1.0f / (0.07f + 1e-8f); }

__device__ __forceinline__ void jac(int a, int b, float& mv, float& mk) {
    int u = __popc(a & b);
    int l = __popc(a | b);
    mv = (float)u / ((float)l + 1e-8f);
    mk = (mv >= 0.3f) ? 1.0f : 0.0f;
}

__device__ __forceinline__ ushort bf16rne(float x) {
    uint u = __float_as_uint(x);
    u += 0x7FFF + ((u >> 16) & 1);
    return (ushort)(u >> 16);
}

// ---------------- K0: zero accumulators ----------------
__global__ void k_zero(float* F, int* count) {
    int t = threadIdx.x;
    for (int i = t; i < NCLS * D_DIM; i += 256) F[i] = 0.0f;
    if (t < NCLS) count[t] = 0;
}

// ---------------- K1: fused label-pack + bf16 cast + per-class sums + row norms ----------------
// grid 128 blocks x 256 thr; block b handles rows n0..n0+63 (one view).
__global__ void k_castfeat(const float* __restrict__ feats, const int* __restrict__ labels,
                           int* __restrict__ cls, int* __restrict__ count,
                           float* __restrict__ F, ushort* __restrict__ fb,
                           float* __restrict__ nrm2v) {
    __shared__ float loc[NCLS * D_DIM];   // 32 KiB
    __shared__ int cls_loc[64];
    int b = blockIdx.x;
    int t = threadIdx.x;
    int n0 = b * 64;
    int s0 = n0 & (B_SAMP - 1);
    int view = n0 >> 12;
    for (int i = t; i < NCLS * D_DIM; i += 256) loc[i] = 0.0f;
    if (t < 64) {
        int c = 0;
#pragma unroll
        for (int k = 0; k < 6; k++) c |= (labels[(s0 + t) * 6 + k] != 0) << k;
        cls_loc[t] = c;
        if (view == 0) { cls[s0 + t] = c; atomicAdd(&count[c], 1); }
    }
    __syncthreads();
    // 64 rows x 32 float4 quads
    for (int q = t; q < 64 * 32; q += 256) {
        int r = q >> 5, d4 = (q & 31) * 4;
        const float* src = feats + (size_t)(s0 + r) * 256 + (size_t)view * 128 + d4;
        float4 v = *(const float4*)src;
        ushort4 h;
        h.x = bf16rne(v.x); h.y = bf16rne(v.y); h.z = bf16rne(v.z); h.w = bf16rne(v.w);
        *(ushort4*)&fb[(size_t)(n0 + r) * D_DIM + d4] = h;
        float* lrow = &loc[cls_loc[r] * D_DIM + d4];
        atomicAdd(&lrow[0], v.x); atomicAdd(&lrow[1], v.y);
        atomicAdd(&lrow[2], v.z); atomicAdd(&lrow[3], v.w);
        // fp32 row norm^2 -> exact diagonal logit (the row-max candidate) for k_gemm's m-init
        float qs = v.x * v.x + v.y * v.y + v.z * v.z + v.w * v.w;
#pragma unroll
        for (int o = 16; o; o >>= 1) qs += __shfl_xor(qs, o);
        if ((t & 31) == 0) nrm2v[n0 + r] = qs;
    }
    __syncthreads();
    for (int i = t; i < NCLS * D_DIM; i += 256) {
        float v = loc[i];
        if (v != 0.0f) atomicAdd(&F[i], v);
    }
}

// ---------------- K2: class tables G, Wm, W, diag terms ----------------
__global__ void k_tables(const float* __restrict__ F, const int* __restrict__ count,
                         float* G, float* WmC, float* WC, float* gdiag, float* mdiag) {
    int c = blockIdx.x;
    int d = threadIdx.x;
    float sum = 0.0f;
    for (int c2 = 0; c2 < NCLS; c2++) {
        float mv, mk; jac(c, c2, mv, mk);
        sum += mv * mk * F[c2 * D_DIM + d];
    }
    G[c * D_DIM + d] = sum;
    if (d == 0) {
        float wm = 0.0f, wv = 0.0f;
        for (int c2 = 0; c2 < NCLS; c2++) {
            float mv, mk; jac(c, c2, mv, mk);
            float cnt2 = 2.0f * (float)count[c2];
            wm += mv * mk * cnt2;
            wv += mk * cnt2;
        }
        float mv, mk; jac(c, c, mv, mk);
        WmC[c] = wm; WC[c] = wv; gdiag[c] = mv * mk; mdiag[c] = mk;
    }
}

// ---------------- K3: bf16 MFMA GEMM, whole-chunk LDS staging, no in-loop sync ----------------
// Rounds 3-5 lesson: every variant that re-fetched B per 64-col tile inside the
// dependence chain (LDS+barrier or global-direct) pinned at 41-47us, MFMA ~14%,
// occ ~9% -- latency-bound. Fix: stage the block's ENTIRE 512-col B-chunk (128 KiB)
// into LDS once (one barrier), then 8 barrier-free ds_read+MFMA tiles per wave.
// Geometry per guide m201: 256 blocks (16 rowBlk x 16 chunks) x 512 thr (8 waves),
// 1 block/CU, 2 waves/SIMD. LDS is k-slice-major [16][512 cols x 8 ushort] so
// global_load_lds dest is linear (lane-consecutive cols) and ds_read_b128 by
// 16 consecutive cols is conflict-free.
__launch_bounds__(512, 2)
__global__ void k_gemm6(const ushort* __restrict__ fb, const float* __restrict__ nrm2v,
                        float* __restrict__ pm, float* __restrict__ ps) {
    __shared__ ushort Bs[16][CCHUNK * 8];   // 16 k-slices x (512 cols x 8 ushort) = 128 KiB
    const float invT = inv_temp();
    int tid = threadIdx.x;
    int lane = tid & 63, w = tid >> 6;          // 8 waves
    int rowBlk = blockIdx.x & 15;
    int chunk  = blockIdx.x >> 4;
    int rowbase = rowBlk * 512 + w * 64;
    int colChunk = chunk * CCHUNK;
    int r0 = (lane >> 4) * 4;

    // A fragments (global, L2): lane holds row rowbase+rf*16+(lane&15), k = kk*32+(lane>>4)*8
    short8 a[4][4];
    {
        int r = lane & 15, kb = (lane >> 4) * 8;
#pragma unroll
        for (int rf = 0; rf < 4; rf++)
#pragma unroll
            for (int kk = 0; kk < 4; kk++)
                a[rf][kk] = *(const short8*)&fb[(size_t)(rowbase + rf * 16 + r) * D_DIM + kk * 32 + kb];
    }

    float m[16], s[16];
#pragma unroll
    for (int rf = 0; rf < 4; rf++)
#pragma unroll
        for (int r = 0; r < 4; r++) {
            m[rf * 4 + r] = nrm2v[rowbase + rf * 16 + r0 + r];
            s[rf * 4 + r] = 0.0f;
        }

    // Stage whole chunk: wave w stages cols [w*64, w*64+64), all 16 k-slices.
    // dest (wave-uniform base + lane*16B): Bs[j][ (w*64+lane)*8 ]; src per-lane scattered.
#pragma unroll
    for (int j = 0; j < 16; j++) {
        const ushort* g = fb + (size_t)(colChunk + w * 64 + lane) * D_DIM + j * 8;
        __builtin_amdgcn_global_load_lds((const __attribute__((address_space(1))) void*)g,
            (__attribute__((address_space(3))) void*)&Bs[j][w * 64 * 8], 16, 0, 0);
    }
    __syncthreads();   // the only barrier

    for (int t = 0; t < NTILE; t++) {
        f32x4 acc[4][4];
#pragma unroll
        for (int rf = 0; rf < 4; rf++)
#pragma unroll
            for (int cf = 0; cf < 4; cf++)
                acc[rf][cf] = (f32x4){0.f, 0.f, 0.f, 0.f};

#pragma unroll
        for (int cf = 0; cf < 4; cf++) {
            int col = t * TC + cf * 16 + (lane & 15);
            short8 b[4];
#pragma unroll
            for (int kk = 0; kk < 4; kk++) {
                int jj = kk * 4 + (lane >> 4);
                b[kk] = *(const short8*)&Bs[jj][col * 8];
            }
#pragma unroll
            for (int rf = 0; rf < 4; rf++)
#pragma unroll
                for (int kk = 0; kk < 4; kk++)
                    acc[rf][cf] = __builtin_amdgcn_mfma_f32_16x16x32_bf16(a[rf][kk], b[kk], acc[rf][cf], 0, 0, 0);
        }

        // wave-uniform activity test: any idx whose tile-max encroaches on its running max
        float tmax[16];
        int act = 0;
#pragma unroll
        for (int rf = 0; rf < 4; rf++)
#pragma unroll
            for (int r = 0; r < 4; r++) {
                int idx = rf * 4 + r;
                float t0 = fmaxf(acc[rf][0][r], acc[rf][1][r]);
                float t1 = fmaxf(acc[rf][2][r], acc[rf][3][r]);
                tmax[idx] = fmaxf(t0, t1);
                act |= (tmax[idx] > m[idx] - THR_DOT) ? 1 : 0;
            }
        if (__any(act)) {
            int tileCol = colChunk + t * TC + (lane & 15);
#pragma unroll
            for (int rf = 0; rf < 4; rf++)
#pragma unroll
                for (int r = 0; r < 4; r++) {
                    int idx = rf * 4 + r;
                    int grow = rowbase + rf * 16 + r0 + r;
                    float nm = fmaxf(m[idx], tmax[idx]);
                    float sc = __expf((m[idx] - nm) * invT);
                    float v0 = acc[rf][0][r], v1 = acc[rf][1][r], v2 = acc[rf][2][r], v3 = acc[rf][3][r];
                    float e0 = (tileCol      == grow) ? 0.f : __expf((v0 - nm) * invT);
                    float e1 = (tileCol + 16 == grow) ? 0.f : __expf((v1 - nm) * invT);
                    float e2 = (tileCol + 32 == grow) ? 0.f : __expf((v2 - nm) * invT);
                    float e3 = (tileCol + 48 == grow) ? 0.f : __expf((v3 - nm) * invT);
                    s[idx] = s[idx] * sc + ((e0 + e1) + (e2 + e3));
                    m[idx] = nm;
                }
        }
    }

    // merge the 16 col-slot partials (xor over low 4 lane bits)
#pragma unroll
    for (int i = 0; i < 16; i++) {
#pragma unroll
        for (int off = 1; off < 16; off <<= 1) {
            float om = __shfl_xor(m[i], off);
            float os = __shfl_xor(s[i], off);
            float nm = fmaxf(m[i], om);
            s[i] = s[i] * __expf((m[i] - nm) * invT) + os * __expf((om - nm) * invT);
            m[i] = nm;
        }
    }
    if ((lane & 15) == 0) {
#pragma unroll
        for (int rf = 0; rf < 4; rf++)
#pragma unroll
            for (int r = 0; r < 4; r++) {
                int grow = rowbase + rf * 16 + r0 + r;
                pm[chunk * N_ROWS + grow] = m[rf * 4 + r];
                ps[chunk * N_ROWS + grow] = s[rf * 4 + r];
            }
    }
}

// ---------------- K4: fused chunk-merge + f.G / ||f||^2 + per-row loss ----------------
// grid 2048 x 256: one wave per row.
__global__ void k_final2(const float* __restrict__ feats, const int* __restrict__ cls,
                         const float* __restrict__ G, const float* __restrict__ pm,
                         const float* __restrict__ ps, const float* __restrict__ WmC,
                         const float* __restrict__ WC, const float* __restrict__ gdiag,
                         const float* __restrict__ mdiag, float* __restrict__ partial) {
    const float invT = inv_temp();
    __shared__ float red[4];
    int tid = threadIdx.x;
    int lane = tid & 63, w = tid >> 6;
    int n = blockIdx.x * 4 + w;
    int samp = n & (B_SAMP - 1), view = n >> 12;
    int c = cls[samp];
    const float* f = feats + (size_t)samp * 256 + (size_t)view * 128;
    const float* g = G + (size_t)c * D_DIM;
    float2 fv = *(const float2*)(f + lane * 2);
    float2 gv = *(const float2*)(g + lane * 2);
    float dg = fv.x * gv.x + fv.y * gv.y;
    float nn = fv.x * fv.x + fv.y * fv.y;
#pragma unroll
    for (int o = 32; o; o >>= 1) { dg += __shfl_down(dg, o); nn += __shfl_down(nn, o); }
    dg = __shfl(dg, 0); nn = __shfl(nn, 0);

    float m = -INFINITY, s = 0.0f;
    if (lane < 16) { m = pm[lane * N_ROWS + n]; s = ps[lane * N_ROWS + n]; }
#pragma unroll
    for (int off = 8; off; off >>= 1) {
        float om = __shfl_xor(m, off);
        float os = __shfl_xor(s, off);
        float nm = fmaxf(m, om);
        s = s * __expf((m - nm) * invT) + os * __expf((om - nm) * invT);
        m = nm;
    }
    if (lane == 0) {
        float wm = WmC[c] - gdiag[c];
        float wv = WC[c] - mdiag[c];
        float swl = (dg - gdiag[c] * nn) * invT;
        float lp = swl - wm * (m * invT) - wm * logf(s + 1e-8f);
        red[w] = -lp / (wv + 1e-8f);
    }
    __syncthreads();
    if (tid == 0) partial[blockIdx.x] = (red[0] + red[1]) + (red[2] + red[3]);
}

// ---------------- K5: final deterministic reduce ----------------
__global__ void k_out(const float* __restrict__ partial, float* out) {
    __shared__ float red[4];
    int t = threadIdx.x;
    float s = 0.0f;
    for (int i = t; i < 2048; i += 256) s += partial[i];
#pragma unroll
    for (int o = 32; o; o >>= 1) s += __shfl_down(s, o);
    if ((t & 63) == 0) red[t >> 6] = s;
    __syncthreads();
    if (t == 0) out[0] = ((red[0] + red[1]) + (red[2] + red[3])) / (float)N_ROWS;
}

extern "C" void kernel_launch(void* const* d_in, const int* in_sizes, int n_in,
                              void* d_out, int out_size, void* d_ws, size_t ws_size,
                              hipStream_t stream) {
    const float* feats  = (const float*)d_in[0];
    const int*   labels = (const int*)d_in[1];
    float* out = (float*)d_out;

    char* ws = (char*)d_ws;
    ushort* fb    = (ushort*)ws;              ws += (size_t)N_ROWS * D_DIM * 2;      // 2 MiB
    float* pm     = (float*)ws;               ws += (size_t)NCHUNK * N_ROWS * 4;     // 512 KiB
    float* ps     = (float*)ws;               ws += (size_t)NCHUNK * N_ROWS * 4;     // 512 KiB
    int*   cls    = (int*)ws;                 ws += B_SAMP * 4;
    int*   count  = (int*)ws;                 ws += NCLS * 4;
    float* F      = (float*)ws;               ws += NCLS * D_DIM * 4;
    float* G      = (float*)ws;               ws += NCLS * D_DIM * 4;
    float* WmC    = (float*)ws;               ws += NCLS * 4;
    float* WC     = (float*)ws;               ws += NCLS * 4;
    float* gdiag  = (float*)ws;               ws += NCLS * 4;
    float* mdiag  = (float*)ws;               ws += NCLS * 4;
    float* nrm2v  = (float*)ws;               ws += N_ROWS * 4;
    float* partial= (float*)ws;               ws += 2048 * 4;

    k_zero    <<<1, 256, 0, stream>>>(F, count);
    k_castfeat<<<128, 256, 0, stream>>>(feats, labels, cls, count, F, fb, nrm2v);
    k_tables  <<<NCLS, 128, 0, stream>>>(F, count, G, WmC, WC, gdiag, mdiag);
    k_gemm6   <<<256, 512, 0, stream>>>(fb, nrm2v, pm, ps);
    k_final2  <<<2048, 256, 0, stream>>>(feats, cls, G, pm, ps, WmC, WC, gdiag, mdiag, partial);
    k_out     <<<1, 256, 0, stream>>>(partial, out);
}

// Round 7
// 74.834 us; speedup vs baseline: 1.3219x; 1.0342x over previous
//
#include <hip/hip_runtime.h>
#include <cstdint>
#include <math.h>

#define B_SAMP 4096
#define D_DIM  128
#define N_ROWS 8192
#define NCLS   64
#define NCHUNK 16
#define CCHUNK 512
#define TC     64
#define NTILE  (CCHUNK / TC)
#define THR_DOT 2.1f   // = 30 logit units; dropped terms < e^-30 relative to running max

typedef __attribute__((ext_vector_type(8))) short short8;
typedef __attribute__((ext_vector_type(4))) float f32x4;

__device__ __forceinline__ float inv_temp() { return 1.0f / (0.07f + 1e-8f); }

__device__ __forceinline__ void jac(int a, int b, float& mv, float& mk) {
    int u = __popc(a & b);
    int l = __popc(a | b);
    mv = (float)u / ((float)l + 1e-8f);
    mk = (mv >= 0.3f) ? 1.0f : 0.0f;
}

__device__ __forceinline__ ushort bf16rne(float x) {
    uint u = __float_as_uint(x);
    u += 0x7FFF + ((u >> 16) & 1);
    return (ushort)(u >> 16);
}

// ---------------- K1: class-per-block cast + class sums + norms ----------------
// Round-6 lesson: the old flush (1M same-address global atomicAdds onto 32KB F)
// was L2-RMW-serialized. Block c owns class c: compact its samples, register-sum
// F[c], plain stores only. Also removes k_zero (F/count fully written here).
__global__ void k_castfeat2(const float* __restrict__ feats, const int* __restrict__ labels,
                            int* __restrict__ cls, int* __restrict__ count, float* __restrict__ F,
                            ushort* __restrict__ fb, float* __restrict__ nrm2v) {
    __shared__ int list[B_SAMP];      // worst case: every sample in this class (16 KiB)
    __shared__ float fsum[4][D_DIM];  // per-wave partials
    __shared__ int lcnt;
    int c = blockIdx.x, t = threadIdx.x, lane = t & 63, w = t >> 6;
    if (t == 0) lcnt = 0;
    __syncthreads();
    for (int s = t; s < B_SAMP; s += 256) {
        int code = 0;
#pragma unroll
        for (int k = 0; k < 6; k++) code |= (labels[s * 6 + k] != 0) << k;
        if (code == c) {
            int idx = atomicAdd(&lcnt, 1);
            list[idx] = s;
            cls[s] = c;
        }
    }
    __syncthreads();
    int cnt = lcnt;
    if (t == 0) count[c] = cnt;
    // rows = 2*cnt (both views); wave handles one row at a time, lane = dims 2l,2l+1
    float2 acc = make_float2(0.f, 0.f);
    for (int i = w; i < 2 * cnt; i += 4) {
        int s = list[i >> 1];
        int v = i & 1;
        const float* src = feats + (size_t)s * 256 + (size_t)v * 128;
        float2 fv = *(const float2*)(src + lane * 2);
        acc.x += fv.x; acc.y += fv.y;
        ushort2 h; h.x = bf16rne(fv.x); h.y = bf16rne(fv.y);
        *(ushort2*)&fb[(size_t)(v * B_SAMP + s) * D_DIM + lane * 2] = h;
        float qs = fv.x * fv.x + fv.y * fv.y;
#pragma unroll
        for (int o = 32; o; o >>= 1) qs += __shfl_xor(qs, o);
        if (lane == 0) nrm2v[v * B_SAMP + s] = qs;
    }
    fsum[w][lane * 2] = acc.x;
    fsum[w][lane * 2 + 1] = acc.y;
    __syncthreads();
    if (t < D_DIM)
        F[c * D_DIM + t] = (fsum[0][t] + fsum[1][t]) + (fsum[2][t] + fsum[3][t]);
}

// ---------------- K2: class tables G, Wm, W, diag terms ----------------
__global__ void k_tables(const float* __restrict__ F, const int* __restrict__ count,
                         float* G, float* WmC, float* WC, float* gdiag, float* mdiag) {
    int c = blockIdx.x;
    int d = threadIdx.x;
    float sum = 0.0f;
    for (int c2 = 0; c2 < NCLS; c2++) {
        float mv, mk; jac(c, c2, mv, mk);
        sum += mv * mk * F[c2 * D_DIM + d];
    }
    G[c * D_DIM + d] = sum;
    if (d == 0) {
        float wm = 0.0f, wv = 0.0f;
        for (int c2 = 0; c2 < NCLS; c2++) {
            float mv, mk; jac(c, c2, mv, mk);
            float cnt2 = 2.0f * (float)count[c2];
            wm += mv * mk * cnt2;
            wv += mk * cnt2;
        }
        float mv, mk; jac(c, c, mv, mk);
        WmC[c] = wm; WC[c] = wv; gdiag[c] = mv * mk; mdiag[c] = mk;
    }
}

// ---------------- K3: bf16 MFMA GEMM, whole-chunk LDS, reg-dbuf B + setprio ----------------
// 256 blocks (16 rowBlk x 16 chunks) x 512 thr (8 waves), LDS 128 KiB staged once,
// then 8 barrier-free tiles/wave. New vs round 6: B fragments double-buffered in
// registers (loads for cf+1 issued BEFORE the MFMA cluster of cf) and s_setprio(1)
// around each 16-MFMA cluster (waves are barrier-free -> role-diverse, T5 regime).
__launch_bounds__(512, 2)
__global__ void k_gemm7(const ushort* __restrict__ fb, const float* __restrict__ nrm2v,
                        float* __restrict__ pm, float* __restrict__ ps) {
    __shared__ ushort Bs[16][CCHUNK * 8];   // 16 k-slices x (512 cols x 8 ushort) = 128 KiB
    const float invT = inv_temp();
    int tid = threadIdx.x;
    int lane = tid & 63, w = tid >> 6;
    int rowBlk = blockIdx.x & 15;
    int chunk  = blockIdx.x >> 4;
    int rowbase = rowBlk * 512 + w * 64;
    int colChunk = chunk * CCHUNK;
    int r0 = (lane >> 4) * 4;

    // A fragments (global, L2): lane holds row rowbase+rf*16+(lane&15), k = kk*32+(lane>>4)*8
    short8 a[4][4];
    {
        int r = lane & 15, kb = (lane >> 4) * 8;
#pragma unroll
        for (int rf = 0; rf < 4; rf++)
#pragma unroll
            for (int kk = 0; kk < 4; kk++)
                a[rf][kk] = *(const short8*)&fb[(size_t)(rowbase + rf * 16 + r) * D_DIM + kk * 32 + kb];
    }

    float m[16], s[16];
#pragma unroll
    for (int rf = 0; rf < 4; rf++)
#pragma unroll
        for (int r = 0; r < 4; r++) {
            m[rf * 4 + r] = nrm2v[rowbase + rf * 16 + r0 + r];
            s[rf * 4 + r] = 0.0f;
        }

    // Stage whole chunk: wave w stages cols [w*64, w*64+64), all 16 k-slices.
#pragma unroll
    for (int j = 0; j < 16; j++) {
        const ushort* g = fb + (size_t)(colChunk + w * 64 + lane) * D_DIM + j * 8;
        __builtin_amdgcn_global_load_lds((const __attribute__((address_space(1))) void*)g,
            (__attribute__((address_space(3))) void*)&Bs[j][w * 64 * 8], 16, 0, 0);
    }
    __syncthreads();   // the only barrier

    short8 b0[4], b1[4];
    // ds_read helper: 4 k-fragments for column-group cf of tile t
#define LDB(dst, tt, cf)                                                        \
    {                                                                           \
        int col_ = (tt) * TC + (cf) * 16 + (lane & 15);                         \
        _Pragma("unroll")                                                       \
        for (int kk = 0; kk < 4; kk++)                                          \
            dst[kk] = *(const short8*)&Bs[kk * 4 + (lane >> 4)][col_ * 8];      \
    }
#define MFMA16(bb, cf)                                                          \
    {                                                                           \
        __builtin_amdgcn_s_setprio(1);                                          \
        _Pragma("unroll")                                                       \
        for (int rf = 0; rf < 4; rf++)                                          \
            _Pragma("unroll")                                                   \
            for (int kk = 0; kk < 4; kk++)                                      \
                acc[rf][cf] = __builtin_amdgcn_mfma_f32_16x16x32_bf16(          \
                    a[rf][kk], bb[kk], acc[rf][cf], 0, 0, 0);                   \
        __builtin_amdgcn_s_setprio(0);                                          \
    }

    LDB(b0, 0, 0);   // prologue: tile 0, cf 0
    for (int t = 0; t < NTILE; t++) {
        f32x4 acc[4][4];
#pragma unroll
        for (int rf = 0; rf < 4; rf++)
#pragma unroll
            for (int cf = 0; cf < 4; cf++)
                acc[rf][cf] = (f32x4){0.f, 0.f, 0.f, 0.f};

        LDB(b1, t, 1);                       // issue cf1 loads
        MFMA16(b0, 0);                       // compute cf0
        LDB(b0, t, 2);
        MFMA16(b1, 1);
        LDB(b1, t, 3);
        MFMA16(b0, 2);
        { int tn = (t + 1 < NTILE) ? t + 1 : 0; LDB(b0, tn, 0); }  // next tile's cf0
        MFMA16(b1, 3);

        // wave-uniform activity test: any idx whose tile-max encroaches on its running max
        float tmax[16];
        int act = 0;
#pragma unroll
        for (int rf = 0; rf < 4; rf++)
#pragma unroll
            for (int r = 0; r < 4; r++) {
                int idx = rf * 4 + r;
                float t0 = fmaxf(acc[rf][0][r], acc[rf][1][r]);
                float t1 = fmaxf(acc[rf][2][r], acc[rf][3][r]);
                tmax[idx] = fmaxf(t0, t1);
                act |= (tmax[idx] > m[idx] - THR_DOT) ? 1 : 0;
            }
        if (__any(act)) {
            int tileCol = colChunk + t * TC + (lane & 15);
#pragma unroll
            for (int rf = 0; rf < 4; rf++)
#pragma unroll
                for (int r = 0; r < 4; r++) {
                    int idx = rf * 4 + r;
                    int grow = rowbase + rf * 16 + r0 + r;
                    float nm = fmaxf(m[idx], tmax[idx]);
                    float sc = __expf((m[idx] - nm) * invT);
                    float v0 = acc[rf][0][r], v1 = acc[rf][1][r], v2 = acc[rf][2][r], v3 = acc[rf][3][r];
                    float e0 = (tileCol      == grow) ? 0.f : __expf((v0 - nm) * invT);
                    float e1 = (tileCol + 16 == grow) ? 0.f : __expf((v1 - nm) * invT);
                    float e2 = (tileCol + 32 == grow) ? 0.f : __expf((v2 - nm) * invT);
                    float e3 = (tileCol + 48 == grow) ? 0.f : __expf((v3 - nm) * invT);
                    s[idx] = s[idx] * sc + ((e0 + e1) + (e2 + e3));
                    m[idx] = nm;
                }
        }
    }
#undef LDB
#undef MFMA16

    // merge the 16 col-slot partials (xor over low 4 lane bits)
#pragma unroll
    for (int i = 0; i < 16; i++) {
#pragma unroll
        for (int off = 1; off < 16; off <<= 1) {
            float om = __shfl_xor(m[i], off);
            float os = __shfl_xor(s[i], off);
            float nm = fmaxf(m[i], om);
            s[i] = s[i] * __expf((m[i] - nm) * invT) + os * __expf((om - nm) * invT);
            m[i] = nm;
        }
    }
    if ((lane & 15) == 0) {
#pragma unroll
        for (int rf = 0; rf < 4; rf++)
#pragma unroll
            for (int r = 0; r < 4; r++) {
                int grow = rowbase + rf * 16 + r0 + r;
                pm[chunk * N_ROWS + grow] = m[rf * 4 + r];
                ps[chunk * N_ROWS + grow] = s[rf * 4 + r];
            }
    }
}

// ---------------- K4: fused chunk-merge + f.G / ||f||^2 + per-row loss ----------------
__global__ void k_final2(const float* __restrict__ feats, const int* __restrict__ cls,
                         const float* __restrict__ G, const float* __restrict__ pm,
                         const float* __restrict__ ps, const float* __restrict__ WmC,
                         const float* __restrict__ WC, const float* __restrict__ gdiag,
                         const float* __restrict__ mdiag, float* __restrict__ partial) {
    const float invT = inv_temp();
    __shared__ float red[4];
    int tid = threadIdx.x;
    int lane = tid & 63, w = tid >> 6;
    int n = blockIdx.x * 4 + w;
    int samp = n & (B_SAMP - 1), view = n >> 12;
    int c = cls[samp];
    const float* f = feats + (size_t)samp * 256 + (size_t)view * 128;
    const float* g = G + (size_t)c * D_DIM;
    float2 fv = *(const float2*)(f + lane * 2);
    float2 gv = *(const float2*)(g + lane * 2);
    float dg = fv.x * gv.x + fv.y * gv.y;
    float nn = fv.x * fv.x + fv.y * fv.y;
#pragma unroll
    for (int o = 32; o; o >>= 1) { dg += __shfl_down(dg, o); nn += __shfl_down(nn, o); }
    dg = __shfl(dg, 0); nn = __shfl(nn, 0);

    float m = -INFINITY, s = 0.0f;
    if (lane < 16) { m = pm[lane * N_ROWS + n]; s = ps[lane * N_ROWS + n]; }
#pragma unroll
    for (int off = 8; off; off >>= 1) {
        float om = __shfl_xor(m, off);
        float os = __shfl_xor(s, off);
        float nm = fmaxf(m, om);
        s = s * __expf((m - nm) * invT) + os * __expf((om - nm) * invT);
        m = nm;
    }
    if (lane == 0) {
        float wm = WmC[c] - gdiag[c];
        float wv = WC[c] - mdiag[c];
        float swl = (dg - gdiag[c] * nn) * invT;
        float lp = swl - wm * (m * invT) - wm * logf(s + 1e-8f);
        red[w] = -lp / (wv + 1e-8f);
    }
    __syncthreads();
    if (tid == 0) partial[blockIdx.x] = (red[0] + red[1]) + (red[2] + red[3]);
}

// ---------------- K5: final deterministic reduce ----------------
__global__ void k_out(const float* __restrict__ partial, float* out) {
    __shared__ float red[4];
    int t = threadIdx.x;
    float s = 0.0f;
    for (int i = t; i < 2048; i += 256) s += partial[i];
#pragma unroll
    for (int o = 32; o; o >>= 1) s += __shfl_down(s, o);
    if ((t & 63) == 0) red[t >> 6] = s;
    __syncthreads();
    if (t == 0) out[0] = ((red[0] + red[1]) + (red[2] + red[3])) / (float)N_ROWS;
}

extern "C" void kernel_launch(void* const* d_in, const int* in_sizes, int n_in,
                              void* d_out, int out_size, void* d_ws, size_t ws_size,
                              hipStream_t stream) {
    const float* feats  = (const float*)d_in[0];
    const int*   labels = (const int*)d_in[1];
    float* out = (float*)d_out;

    char* ws = (char*)d_ws;
    ushort* fb    = (ushort*)ws;              ws += (size_t)N_ROWS * D_DIM * 2;      // 2 MiB
    float* pm     = (float*)ws;               ws += (size_t)NCHUNK * N_ROWS * 4;     // 512 KiB
    float* ps     = (float*)ws;               ws += (size_t)NCHUNK * N_ROWS * 4;     // 512 KiB
    int*   cls    = (int*)ws;                 ws += B_SAMP * 4;
    int*   count  = (int*)ws;                 ws += NCLS * 4;
    float* F      = (float*)ws;               ws += NCLS * D_DIM * 4;
    float* G      = (float*)ws;               ws += NCLS * D_DIM * 4;
    float* WmC    = (float*)ws;               ws += NCLS * 4;
    float* WC     = (float*)ws;               ws += NCLS * 4;
    float* gdiag  = (float*)ws;               ws += NCLS * 4;
    float* mdiag  = (float*)ws;               ws += NCLS * 4;
    float* nrm2v  = (float*)ws;               ws += N_ROWS * 4;
    float* partial= (float*)ws;               ws += 2048 * 4;

    k_castfeat2<<<NCLS, 256, 0, stream>>>(feats, labels, cls, count, F, fb, nrm2v);
    k_tables   <<<NCLS, 128, 0, stream>>>(F, count, G, WmC, WC, gdiag, mdiag);
    k_gemm7    <<<256, 512, 0, stream>>>(fb, nrm2v, pm, ps);
    k_final2   <<<2048, 256, 0, stream>>>(feats, cls, G, pm, ps, WmC, WC, gdiag, mdiag, partial);
    k_out      <<<1, 256, 0, stream>>>(partial, out);
}